// Round 1
// baseline (4188.407 us; speedup 1.0000x reference)
//
#include <hip/hip_runtime.h>

#define N_NODES  50000
#define R_REL    3
#define E_EDGES  50000
#define EP_EDGES 100000

static inline int cdiv_h(int a, int b) { return (a + b - 1) / b; }

// ---------------- degrees / norms ----------------
__global__ void deg_all_kernel(const int* __restrict__ src, const int* __restrict__ dst,
                               float* __restrict__ degout, float* __restrict__ degin) {
    int i = blockIdx.x * blockDim.x + threadIdx.x;
    if (i >= R_REL * E_EDGES) return;
    int r = i / E_EDGES;
    atomicAdd(&degout[r * N_NODES + src[i]], 1.0f);
    atomicAdd(&degin [r * N_NODES + dst[i]], 1.0f);
}

__global__ void norm_all_kernel(float* __restrict__ d, int n) {
    int i = blockIdx.x * blockDim.x + threadIdx.x;
    if (i < n) d[i] = rsqrtf(fmaxf(d[i], 1.0f));
}

// ---------------- GEMM: C[MxNd] = A[MxK] @ B[KxNd], row-major ----------------
// BM=128 BN=64 BK=16, 256 threads, 8x4 micro-tile per thread. K%16==0, Nd%64==0.
__global__ __launch_bounds__(256) void gemm_f32_kernel(
        const float* __restrict__ A, const float* __restrict__ B, float* __restrict__ C,
        int M, int K, int Nd) {
    __shared__ float As[16][132];   // [k][m], padded
    __shared__ float Bs[16][68];    // [k][n], padded

    const int tid = threadIdx.x;
    const int tx  = tid & 15;       // N direction (4 cols each)
    const int ty  = tid >> 4;       // M direction (8 rows each)
    const int n0  = blockIdx.x * 64;
    const int m0  = blockIdx.y * 128;

    const int arow = tid >> 2;            // 0..63
    const int acol = (tid & 3) << 2;      // 0,4,8,12
    const int brow = tid >> 4;            // 0..15
    const int bcol = (tid & 15) << 2;     // 0..60

    float acc[8][4];
#pragma unroll
    for (int i = 0; i < 8; ++i)
#pragma unroll
        for (int j = 0; j < 4; ++j) acc[i][j] = 0.0f;

    const int  am0 = m0 + arow;
    const int  am1 = m0 + arow + 64;
    const bool v0  = am0 < M;
    const bool v1  = am1 < M;

    for (int k0 = 0; k0 < K; k0 += 16) {
        float4 a0 = make_float4(0.f, 0.f, 0.f, 0.f), a1 = a0;
        if (v0) a0 = *(const float4*)&A[(size_t)am0 * K + k0 + acol];
        if (v1) a1 = *(const float4*)&A[(size_t)am1 * K + k0 + acol];
        float4 bv = *(const float4*)&B[(size_t)(k0 + brow) * Nd + n0 + bcol];

        As[acol + 0][arow]      = a0.x;
        As[acol + 1][arow]      = a0.y;
        As[acol + 2][arow]      = a0.z;
        As[acol + 3][arow]      = a0.w;
        As[acol + 0][arow + 64] = a1.x;
        As[acol + 1][arow + 64] = a1.y;
        As[acol + 2][arow + 64] = a1.z;
        As[acol + 3][arow + 64] = a1.w;
        *(float4*)&Bs[brow][bcol] = bv;
        __syncthreads();

#pragma unroll
        for (int k = 0; k < 16; ++k) {
            float4 a_lo = *(const float4*)&As[k][ty * 8];
            float4 a_hi = *(const float4*)&As[k][ty * 8 + 4];
            float4 b    = *(const float4*)&Bs[k][tx * 4];
            float am[8] = {a_lo.x, a_lo.y, a_lo.z, a_lo.w, a_hi.x, a_hi.y, a_hi.z, a_hi.w};
            float bn[4] = {b.x, b.y, b.z, b.w};
#pragma unroll
            for (int i = 0; i < 8; ++i)
#pragma unroll
                for (int j = 0; j < 4; ++j)
                    acc[i][j] = fmaf(am[i], bn[j], acc[i][j]);
        }
        __syncthreads();
    }

#pragma unroll
    for (int i = 0; i < 8; ++i) {
        int m = m0 + ty * 8 + i;
        if (m < M) {
            float4 v = make_float4(acc[i][0], acc[i][1], acc[i][2], acc[i][3]);
            *(float4*)&C[(size_t)m * Nd + n0 + tx * 4] = v;
        }
    }
}

// ---------------- edge scatter: out[dst] += hr[src] * sn[src] * dn[dst] ----------------
__global__ void scatter_kernel(const float* __restrict__ hr, const int* __restrict__ src,
                               const int* __restrict__ dst, const float* __restrict__ sn,
                               const float* __restrict__ dn, float* __restrict__ outbuf,
                               int lgc, int total) {
    int i = blockIdx.x * blockDim.x + threadIdx.x;
    if (i >= total) return;
    int e = i >> lgc;
    int c = i & ((1 << lgc) - 1);
    int s = src[e], d = dst[e];
    float scale = sn[s] * dn[d];
    float4 v = ((const float4*)hr)[((size_t)s << lgc) + c];
    float* o = (float*)(((float4*)outbuf) + (((size_t)d << lgc) + c));
    atomicAdd(o + 0, v.x * scale);
    atomicAdd(o + 1, v.y * scale);
    atomicAdd(o + 2, v.z * scale);
    atomicAdd(o + 3, v.w * scale);
}

// ---------------- bias-sum + optional ReLU ----------------
__global__ void finish_kernel(float* __restrict__ h, const float* __restrict__ b,
                              int dout, int do_relu, int total4) {
    int i = blockIdx.x * blockDim.x + threadIdx.x;
    if (i >= total4) return;
    int cmask = (dout >> 2) - 1;
    int f = (i & cmask) << 2;
    float4 v = ((float4*)h)[i];
    v.x += b[f + 0] + b[dout + f + 0] + b[2 * dout + f + 0];
    v.y += b[f + 1] + b[dout + f + 1] + b[2 * dout + f + 1];
    v.z += b[f + 2] + b[dout + f + 2] + b[2 * dout + f + 2];
    v.w += b[f + 3] + b[dout + f + 3] + b[2 * dout + f + 3];
    if (do_relu) {
        v.x = fmaxf(v.x, 0.f); v.y = fmaxf(v.y, 0.f);
        v.z = fmaxf(v.z, 0.f); v.w = fmaxf(v.w, 0.f);
    }
    ((float4*)h)[i] = v;
}

// ---------------- edge predictor: one wave per edge ----------------
__global__ __launch_bounds__(256) void predict_kernel(
        const float* __restrict__ h, const int* __restrict__ src, const int* __restrict__ dst,
        const float* __restrict__ Wp1, const float* __restrict__ bp1,
        const float* __restrict__ Wp2, const float* __restrict__ bp2,
        float* __restrict__ outp, int n_edges) {
    int gw   = (blockIdx.x * blockDim.x + threadIdx.x) >> 6;
    int lane = threadIdx.x & 63;
    if (gw >= n_edges) return;
    int s = src[gw], d = dst[gw];
    float zs = h[(size_t)s * 64 + lane];
    float zd = h[(size_t)d * 64 + lane];
    float acc = bp1[lane];
#pragma unroll 8
    for (int k = 0; k < 64; ++k)
        acc = fmaf(__shfl(zs, k), Wp1[k * 64 + lane], acc);
#pragma unroll 8
    for (int k = 0; k < 64; ++k)
        acc = fmaf(__shfl(zd, k), Wp1[(64 + k) * 64 + lane], acc);
    float t = fmaxf(acc, 0.f) * Wp2[lane];
#pragma unroll
    for (int off = 32; off; off >>= 1) t += __shfl_down(t, off);
    if (lane == 0) outp[gw] = t + bp2[0];
}

extern "C" void kernel_launch(void* const* d_in, const int* in_sizes, int n_in,
                              void* d_out, int out_size, void* d_ws, size_t ws_size,
                              hipStream_t stream) {
    const float* x       = (const float*)d_in[0];
    const int*   rel_src = (const int*)d_in[1];
    const int*   rel_dst = (const int*)d_in[2];
    const int*   pos_src = (const int*)d_in[3];
    const int*   pos_dst = (const int*)d_in[4];
    const int*   neg_src = (const int*)d_in[5];
    const int*   neg_dst = (const int*)d_in[6];
    const float* W[4]    = {(const float*)d_in[7],  (const float*)d_in[9],
                            (const float*)d_in[11], (const float*)d_in[13]};
    const float* bias[4] = {(const float*)d_in[8],  (const float*)d_in[10],
                            (const float*)d_in[12], (const float*)d_in[14]};
    const float* Wp1 = (const float*)d_in[15];
    const float* bp1 = (const float*)d_in[16];
    const float* Wp2 = (const float*)d_in[17];
    const float* bp2 = (const float*)d_in[18];
    float* out = (float*)d_out;

    float* ws = (float*)d_ws;
    size_t NB = (size_t)N_NODES * 512;
    float* hbuf[2] = {ws, ws + NB};
    float* hr = ws + 2 * NB;
    float* sn = ws + 3 * NB;            // [R][N] degree -> norm (src side)
    float* dn = sn + (size_t)R_REL * N_NODES;  // [R][N] (dst side)

    // degrees -> norms (in place)
    hipMemsetAsync(sn, 0, sizeof(float) * 2 * R_REL * N_NODES, stream);
    deg_all_kernel<<<cdiv_h(R_REL * E_EDGES, 256), 256, 0, stream>>>(rel_src, rel_dst, sn, dn);
    norm_all_kernel<<<cdiv_h(2 * R_REL * N_NODES, 256), 256, 0, stream>>>(sn, 2 * R_REL * N_NODES);

    const int dims[5] = {512, 512, 256, 128, 64};
    const float* hcur = x;
    int cur = 0;
    for (int l = 0; l < 4; ++l) {
        int din = dims[l], dout = dims[l + 1];
        float* hnext = hbuf[cur];
        hipMemsetAsync(hnext, 0, sizeof(float) * (size_t)N_NODES * dout, stream);
        int lgc = (dout == 512) ? 7 : (dout == 256) ? 6 : (dout == 128) ? 5 : 4; // log2(dout/4)
        for (int r = 0; r < R_REL; ++r) {
            dim3 grid(dout / 64, cdiv_h(N_NODES, 128));
            gemm_f32_kernel<<<grid, 256, 0, stream>>>(
                hcur, W[l] + (size_t)r * din * dout, hr, N_NODES, din, dout);
            int total = E_EDGES << lgc;
            scatter_kernel<<<cdiv_h(total, 256), 256, 0, stream>>>(
                hr, rel_src + (size_t)r * E_EDGES, rel_dst + (size_t)r * E_EDGES,
                sn + (size_t)r * N_NODES, dn + (size_t)r * N_NODES, hnext, lgc, total);
        }
        int total4 = N_NODES * dout / 4;
        finish_kernel<<<cdiv_h(total4, 256), 256, 0, stream>>>(
            hnext, bias[l], dout, (l < 3) ? 1 : 0, total4);
        hcur = hnext;
        cur ^= 1;
    }

    // edge predictor: one wave per edge
    int blocks = cdiv_h(EP_EDGES * 64, 256);
    predict_kernel<<<blocks, 256, 0, stream>>>(hcur, pos_src, pos_dst, Wp1, bp1, Wp2, bp2,
                                               out, EP_EDGES);
    predict_kernel<<<blocks, 256, 0, stream>>>(hcur, neg_src, neg_dst, Wp1, bp1, Wp2, bp2,
                                               out + EP_EDGES, EP_EDGES);
}

// Round 2
// 2475.227 us; speedup vs baseline: 1.6921x; 1.6921x over previous
//
#include <hip/hip_runtime.h>

#define N_NODES  50000
#define R_REL    3
#define E_EDGES  50000
#define EP_EDGES 100000
#define ELL_CAP  32

static inline int cdiv_h(int a, int b) { return (a + b - 1) / b; }

// ---------------- degree count + ELL fill ----------------
// outcnt/incnt: [R][N] ints (zeroed). ell: [R][N][ELL_CAP] src indices.
__global__ void count_fill_kernel(const int* __restrict__ src, const int* __restrict__ dst,
                                  int* __restrict__ outcnt, int* __restrict__ incnt,
                                  int* __restrict__ ell) {
    int i = blockIdx.x * blockDim.x + threadIdx.x;
    if (i >= R_REL * E_EDGES) return;
    int r = i / E_EDGES;
    int s = src[i], d = dst[i];
    atomicAdd(&outcnt[r * N_NODES + s], 1);
    int k = atomicAdd(&incnt[r * N_NODES + d], 1);
    if (k < ELL_CAP)
        ell[((size_t)(r * N_NODES + d) << 5) + k] = s;
}

// int degree -> rsqrt norm (float), for both sn and dn arrays
__global__ void norm_kernel(const int* __restrict__ cnt, float* __restrict__ nrm, int n) {
    int i = blockIdx.x * blockDim.x + threadIdx.x;
    if (i < n) nrm[i] = rsqrtf(fmaxf((float)cnt[i], 1.0f));
}

// ---------------- GEMM: C[MxNd] = (A[MxK] @ B[KxNd]) * rowscale[m], row-major ----------------
// BM=128 BN=64 BK=16, 256 threads, 8x4 micro-tile per thread. K%16==0, Nd%64==0.
__global__ __launch_bounds__(256) void gemm_f32_kernel(
        const float* __restrict__ A, const float* __restrict__ B, float* __restrict__ C,
        const float* __restrict__ rowscale, int M, int K, int Nd) {
    __shared__ float As[16][132];   // [k][m], padded
    __shared__ float Bs[16][68];    // [k][n], padded

    const int tid = threadIdx.x;
    const int tx  = tid & 15;       // N direction (4 cols each)
    const int ty  = tid >> 4;       // M direction (8 rows each)
    const int n0  = blockIdx.x * 64;
    const int m0  = blockIdx.y * 128;

    const int arow = tid >> 2;            // 0..63
    const int acol = (tid & 3) << 2;      // 0,4,8,12
    const int brow = tid >> 4;            // 0..15
    const int bcol = (tid & 15) << 2;     // 0..60

    float acc[8][4];
#pragma unroll
    for (int i = 0; i < 8; ++i)
#pragma unroll
        for (int j = 0; j < 4; ++j) acc[i][j] = 0.0f;

    const int  am0 = m0 + arow;
    const int  am1 = m0 + arow + 64;
    const bool v0  = am0 < M;
    const bool v1  = am1 < M;

    for (int k0 = 0; k0 < K; k0 += 16) {
        float4 a0 = make_float4(0.f, 0.f, 0.f, 0.f), a1 = a0;
        if (v0) a0 = *(const float4*)&A[(size_t)am0 * K + k0 + acol];
        if (v1) a1 = *(const float4*)&A[(size_t)am1 * K + k0 + acol];
        float4 bv = *(const float4*)&B[(size_t)(k0 + brow) * Nd + n0 + bcol];

        As[acol + 0][arow]      = a0.x;
        As[acol + 1][arow]      = a0.y;
        As[acol + 2][arow]      = a0.z;
        As[acol + 3][arow]      = a0.w;
        As[acol + 0][arow + 64] = a1.x;
        As[acol + 1][arow + 64] = a1.y;
        As[acol + 2][arow + 64] = a1.z;
        As[acol + 3][arow + 64] = a1.w;
        *(float4*)&Bs[brow][bcol] = bv;
        __syncthreads();

#pragma unroll
        for (int k = 0; k < 16; ++k) {
            float4 a_lo = *(const float4*)&As[k][ty * 8];
            float4 a_hi = *(const float4*)&As[k][ty * 8 + 4];
            float4 b    = *(const float4*)&Bs[k][tx * 4];
            float am[8] = {a_lo.x, a_lo.y, a_lo.z, a_lo.w, a_hi.x, a_hi.y, a_hi.z, a_hi.w};
            float bn[4] = {b.x, b.y, b.z, b.w};
#pragma unroll
            for (int i = 0; i < 8; ++i)
#pragma unroll
                for (int j = 0; j < 4; ++j)
                    acc[i][j] = fmaf(am[i], bn[j], acc[i][j]);
        }
        __syncthreads();
    }

#pragma unroll
    for (int i = 0; i < 8; ++i) {
        int m = m0 + ty * 8 + i;
        if (m < M) {
            float rs = rowscale[m];
            float4 v = make_float4(acc[i][0] * rs, acc[i][1] * rs,
                                   acc[i][2] * rs, acc[i][3] * rs);
            *(float4*)&C[(size_t)m * Nd + n0 + tx * 4] = v;
        }
    }
}

// ---------------- ELL gather: out[d] (+)= dn[d] * sum_{e in-edges} hr[src_e] ----------------
// mode: 0 = init (write), 1 = accumulate, 2 = final (+bias-sum, ReLU), 3 = final (+bias-sum)
__global__ void gather_kernel(const float* __restrict__ hr, const int* __restrict__ ell,
                              const int* __restrict__ cnt, const float* __restrict__ dn,
                              const float* __restrict__ bias, float* __restrict__ out,
                              int lgc, int total, int mode, int dout) {
    int i = blockIdx.x * blockDim.x + threadIdx.x;
    if (i >= total) return;
    int d = i >> lgc;
    int c = i & ((1 << lgc) - 1);
    int nr = cnt[d];
    nr = nr < ELL_CAP ? nr : ELL_CAP;
    size_t base = (size_t)d << 5;
    float4 acc = make_float4(0.f, 0.f, 0.f, 0.f);
    const float4* hr4 = (const float4*)hr;
    for (int k = 0; k < nr; ++k) {
        int s = ell[base + k];
        float4 v = hr4[((size_t)s << lgc) + c];
        acc.x += v.x; acc.y += v.y; acc.z += v.z; acc.w += v.w;
    }
    float dnd = dn[d];
    acc.x *= dnd; acc.y *= dnd; acc.z *= dnd; acc.w *= dnd;
    if (mode >= 2) {
        int f = c << 2;
        acc.x += bias[f + 0] + bias[dout + f + 0] + bias[2 * dout + f + 0];
        acc.y += bias[f + 1] + bias[dout + f + 1] + bias[2 * dout + f + 1];
        acc.z += bias[f + 2] + bias[dout + f + 2] + bias[2 * dout + f + 2];
        acc.w += bias[f + 3] + bias[dout + f + 3] + bias[2 * dout + f + 3];
    }
    if (mode >= 1) {
        float4 prev = ((float4*)out)[i];
        acc.x += prev.x; acc.y += prev.y; acc.z += prev.z; acc.w += prev.w;
    }
    if (mode == 2) {
        acc.x = fmaxf(acc.x, 0.f); acc.y = fmaxf(acc.y, 0.f);
        acc.z = fmaxf(acc.z, 0.f); acc.w = fmaxf(acc.w, 0.f);
    }
    ((float4*)out)[i] = acc;
}

// ---------------- edge predictor: one wave per edge ----------------
__global__ __launch_bounds__(256) void predict_kernel(
        const float* __restrict__ h, const int* __restrict__ src, const int* __restrict__ dst,
        const float* __restrict__ Wp1, const float* __restrict__ bp1,
        const float* __restrict__ Wp2, const float* __restrict__ bp2,
        float* __restrict__ outp, int n_edges) {
    int gw   = (blockIdx.x * blockDim.x + threadIdx.x) >> 6;
    int lane = threadIdx.x & 63;
    if (gw >= n_edges) return;
    int s = src[gw], d = dst[gw];
    float zs = h[(size_t)s * 64 + lane];
    float zd = h[(size_t)d * 64 + lane];
    float acc = bp1[lane];
#pragma unroll 8
    for (int k = 0; k < 64; ++k)
        acc = fmaf(__shfl(zs, k), Wp1[k * 64 + lane], acc);
#pragma unroll 8
    for (int k = 0; k < 64; ++k)
        acc = fmaf(__shfl(zd, k), Wp1[(64 + k) * 64 + lane], acc);
    float t = fmaxf(acc, 0.f) * Wp2[lane];
#pragma unroll
    for (int off = 32; off; off >>= 1) t += __shfl_down(t, off);
    if (lane == 0) outp[gw] = t + bp2[0];
}

extern "C" void kernel_launch(void* const* d_in, const int* in_sizes, int n_in,
                              void* d_out, int out_size, void* d_ws, size_t ws_size,
                              hipStream_t stream) {
    const float* x       = (const float*)d_in[0];
    const int*   rel_src = (const int*)d_in[1];
    const int*   rel_dst = (const int*)d_in[2];
    const int*   pos_src = (const int*)d_in[3];
    const int*   pos_dst = (const int*)d_in[4];
    const int*   neg_src = (const int*)d_in[5];
    const int*   neg_dst = (const int*)d_in[6];
    const float* W[4]    = {(const float*)d_in[7],  (const float*)d_in[9],
                            (const float*)d_in[11], (const float*)d_in[13]};
    const float* bias[4] = {(const float*)d_in[8],  (const float*)d_in[10],
                            (const float*)d_in[12], (const float*)d_in[14]};
    const float* Wp1 = (const float*)d_in[15];
    const float* bp1 = (const float*)d_in[16];
    const float* Wp2 = (const float*)d_in[17];
    const float* bp2 = (const float*)d_in[18];
    float* out = (float*)d_out;

    // workspace layout
    float* ws   = (float*)d_ws;
    size_t NB   = (size_t)N_NODES * 512;
    float* h0   = ws;                  // N x 512
    float* h1   = h0 + NB;             // N x 256 (only ever holds dout<=256)
    float* hr   = h1 + NB / 2;         // N x 512 per-relation GEMM output
    float* sn   = hr + NB;             // [R][N] src-side norms
    float* dn   = sn + (size_t)R_REL * N_NODES;   // [R][N] dst-side norms
    int*   outcnt = (int*)(dn + (size_t)R_REL * N_NODES);  // [R][N]
    int*   incnt  = outcnt + (size_t)R_REL * N_NODES;      // [R][N]
    int*   ell    = incnt + (size_t)R_REL * N_NODES;       // [R][N][ELL_CAP]

    hipMemsetAsync(outcnt, 0, sizeof(int) * 2 * R_REL * N_NODES, stream);
    count_fill_kernel<<<cdiv_h(R_REL * E_EDGES, 256), 256, 0, stream>>>(
        rel_src, rel_dst, outcnt, incnt, ell);
    norm_kernel<<<cdiv_h(R_REL * N_NODES, 256), 256, 0, stream>>>(outcnt, sn, R_REL * N_NODES);
    norm_kernel<<<cdiv_h(R_REL * N_NODES, 256), 256, 0, stream>>>(incnt, dn, R_REL * N_NODES);

    const int dims[5] = {512, 512, 256, 128, 64};
    float* hbufs[4] = {h0, h1, h0, h1};   // shrinking sizes, ping-pong is safe
    const float* hcur = x;
    for (int l = 0; l < 4; ++l) {
        int din = dims[l], dout = dims[l + 1];
        float* hnext = hbufs[l];
        int lgc = (dout == 512) ? 7 : (dout == 256) ? 6 : (dout == 128) ? 5 : 4;
        int total = N_NODES << lgc;
        for (int r = 0; r < R_REL; ++r) {
            dim3 grid(dout / 64, cdiv_h(N_NODES, 128));
            gemm_f32_kernel<<<grid, 256, 0, stream>>>(
                hcur, W[l] + (size_t)r * din * dout, hr, sn + (size_t)r * N_NODES,
                N_NODES, din, dout);
            int mode = (r == 0) ? 0 : (r == 2 ? ((l < 3) ? 2 : 3) : 1);
            gather_kernel<<<cdiv_h(total, 256), 256, 0, stream>>>(
                hr, ell + ((size_t)r * N_NODES << 5), incnt + (size_t)r * N_NODES,
                dn + (size_t)r * N_NODES, bias[l], hnext, lgc, total, mode, dout);
        }
        hcur = hnext;
    }

    // edge predictor: one wave per edge
    int blocks = cdiv_h(EP_EDGES * 64, 256);
    predict_kernel<<<blocks, 256, 0, stream>>>(hcur, pos_src, pos_dst, Wp1, bp1, Wp2, bp2,
                                               out, EP_EDGES);
    predict_kernel<<<blocks, 256, 0, stream>>>(hcur, neg_src, neg_dst, Wp1, bp1, Wp2, bp2,
                                               out + EP_EDGES, EP_EDGES);
}

// Round 3
// 1100.149 us; speedup vs baseline: 3.8071x; 2.2499x over previous
//
#include <hip/hip_runtime.h>

#define N_NODES  50000
#define R_REL    3
#define E_EDGES  50000
#define EP_EDGES 100000
#define ELL_CAP  32

typedef __attribute__((ext_vector_type(8))) short  short8;
typedef __attribute__((ext_vector_type(8))) unsigned short ushort8;
typedef __attribute__((ext_vector_type(4))) float  floatx4;

static inline int cdiv_h(int a, int b) { return (a + b - 1) / b; }

__device__ inline unsigned short f2b(float f) {
    union { float f; unsigned u; } v; v.f = f;
    return (unsigned short)((v.u + 0x7FFF + ((v.u >> 16) & 1)) >> 16);
}
__device__ inline float b2f(unsigned short h) {
    union { unsigned u; float f; } v; v.u = ((unsigned)h) << 16;
    return v.f;
}

#define GLDS16(gp, lp) __builtin_amdgcn_global_load_lds( \
    (const __attribute__((address_space(1))) void*)(gp), \
    (__attribute__((address_space(3))) void*)(lp), 16, 0, 0)

// ---------------- degree count + ELL fill ----------------
__global__ void count_fill_kernel(const int* __restrict__ src, const int* __restrict__ dst,
                                  int* __restrict__ outcnt, int* __restrict__ incnt,
                                  int* __restrict__ ell) {
    int i = blockIdx.x * blockDim.x + threadIdx.x;
    if (i >= R_REL * E_EDGES) return;
    int r = i / E_EDGES;
    int s = src[i], d = dst[i];
    atomicAdd(&outcnt[r * N_NODES + s], 1);
    int k = atomicAdd(&incnt[r * N_NODES + d], 1);
    if (k < ELL_CAP)
        ell[((size_t)(r * N_NODES + d) << 5) + k] = s;
}

__global__ void norm_kernel(const int* __restrict__ cnt, float* __restrict__ nrm, int n) {
    int i = blockIdx.x * blockDim.x + threadIdx.x;
    if (i < n) nrm[i] = rsqrtf(fmaxf((float)cnt[i], 1.0f));
}

// ---------------- fp32 -> bf16 (8 elems/thread) ----------------
__global__ void f2b8_kernel(const float* __restrict__ in, unsigned short* __restrict__ out,
                            int total8) {
    int i = blockIdx.x * blockDim.x + threadIdx.x;
    if (i >= total8) return;
    float4 a = ((const float4*)in)[2 * i];
    float4 b = ((const float4*)in)[2 * i + 1];
    ushort8 o;
    o[0] = f2b(a.x); o[1] = f2b(a.y); o[2] = f2b(a.z); o[3] = f2b(a.w);
    o[4] = f2b(b.x); o[5] = f2b(b.y); o[6] = f2b(b.z); o[7] = f2b(b.w);
    ((ushort8*)out)[i] = o;
}

// ---------------- W[r][k][n] fp32 -> Wt[r][n][k] bf16 ----------------
__global__ void wcvt_kernel(const float* __restrict__ W, unsigned short* __restrict__ Wt,
                            int K, int Nd, int total) {
    int i = blockIdx.x * blockDim.x + threadIdx.x;
    if (i >= total) return;
    int k = i % K;
    int rest = i / K;
    int n = rest % Nd;
    int r = rest / Nd;
    Wt[i] = f2b(W[((size_t)r * K + k) * Nd + n]);
}

// ---------------- MFMA GEMM: C[m][n] = (A[m][:] . Bt[n][:]) * rowscale[m], bf16 in/out ----
// BM=128 BN=64 BK=32, 256 thr (4 waves). A:[M_pad][K] bf16, Bt:[Nd][K] bf16. K%32==0, Nd%64==0.
__global__ __launch_bounds__(256) void gemm_bf16_kernel(
        const unsigned short* __restrict__ A, const unsigned short* __restrict__ Bt,
        unsigned short* __restrict__ C, const float* __restrict__ rowscale,
        int M, int K, int Nd) {
    __shared__ unsigned short sm[4096 + 2048];   // As[128][32], Bs[64][32]
    unsigned short* As = sm;
    unsigned short* Bs = sm + 4096;

    const int tid  = threadIdx.x;
    const int w    = tid >> 6;
    const int lane = tid & 63;
    const int m0   = blockIdx.y * 128;
    const int n0   = blockIdx.x * 64;

    const int lr = lane >> 2;          // 0..15 : row within a 16-row chunk
    const int lc = (lane & 3) * 8;     // k-offset in ushorts (16B chunks)

    floatx4 acc[2][4];
#pragma unroll
    for (int i = 0; i < 2; ++i)
#pragma unroll
        for (int j = 0; j < 4; ++j) acc[i][j] = (floatx4){0.f, 0.f, 0.f, 0.f};

    const int ko   = (lane >> 4) * 8;   // frag k-offset
    const int mrow = lane & 15;

    for (int k0 = 0; k0 < K; k0 += 32) {
#pragma unroll
        for (int s = 0; s < 2; ++s) {
            int q = w + s * 4;   // 16-row chunk of the 128-row A tile
            GLDS16(A + (size_t)(m0 + q * 16 + lr) * K + k0 + lc, As + q * 512);
        }
        GLDS16(Bt + (size_t)(n0 + w * 16 + lr) * K + k0 + lc, Bs + w * 512);
        __syncthreads();

        short8 a0 = *(const short8*)&As[(w * 32 + mrow) * 32 + ko];
        short8 a1 = *(const short8*)&As[(w * 32 + 16 + mrow) * 32 + ko];
        short8 b0 = *(const short8*)&Bs[(mrow) * 32 + ko];
        short8 b1 = *(const short8*)&Bs[(16 + mrow) * 32 + ko];
        short8 b2 = *(const short8*)&Bs[(32 + mrow) * 32 + ko];
        short8 b3 = *(const short8*)&Bs[(48 + mrow) * 32 + ko];

        acc[0][0] = __builtin_amdgcn_mfma_f32_16x16x32_bf16(a0, b0, acc[0][0], 0, 0, 0);
        acc[0][1] = __builtin_amdgcn_mfma_f32_16x16x32_bf16(a0, b1, acc[0][1], 0, 0, 0);
        acc[0][2] = __builtin_amdgcn_mfma_f32_16x16x32_bf16(a0, b2, acc[0][2], 0, 0, 0);
        acc[0][3] = __builtin_amdgcn_mfma_f32_16x16x32_bf16(a0, b3, acc[0][3], 0, 0, 0);
        acc[1][0] = __builtin_amdgcn_mfma_f32_16x16x32_bf16(a1, b0, acc[1][0], 0, 0, 0);
        acc[1][1] = __builtin_amdgcn_mfma_f32_16x16x32_bf16(a1, b1, acc[1][1], 0, 0, 0);
        acc[1][2] = __builtin_amdgcn_mfma_f32_16x16x32_bf16(a1, b2, acc[1][2], 0, 0, 0);
        acc[1][3] = __builtin_amdgcn_mfma_f32_16x16x32_bf16(a1, b3, acc[1][3], 0, 0, 0);
        __syncthreads();
    }

    // epilogue: C/D layout col=lane&15, row=(lane>>4)*4+reg
    const int col   = n0 + (lane & 15);
    const int rbase = m0 + w * 32 + (lane >> 4) * 4;
#pragma unroll
    for (int mi = 0; mi < 2; ++mi) {
#pragma unroll
        for (int reg = 0; reg < 4; ++reg) {
            int row = rbase + mi * 16 + reg;
            if (row < M) {
                float rs = rowscale[row];
#pragma unroll
                for (int nj = 0; nj < 4; ++nj)
                    C[(size_t)row * Nd + col + nj * 16] = f2b(acc[mi][nj][reg] * rs);
            }
        }
    }
}

// ---------------- ELL gather (bf16): out[d] (+)= dn[d] * sum hr[src] ----------------
// mode: 0 init, 1 accumulate, 2 final(+bias,ReLU), 3 final(+bias)
__global__ void gather_kernel(const unsigned short* __restrict__ hr, const int* __restrict__ ell,
                              const int* __restrict__ cnt, const float* __restrict__ dn,
                              const float* __restrict__ bias, unsigned short* __restrict__ outh,
                              int lgc, int total, int mode, int dout) {
    int i = blockIdx.x * blockDim.x + threadIdx.x;
    if (i >= total) return;
    int d = i >> lgc;
    int c = i & ((1 << lgc) - 1);
    int nr = cnt[d];
    nr = nr < ELL_CAP ? nr : ELL_CAP;
    size_t base = (size_t)d << 5;
    float acc[8] = {0.f, 0.f, 0.f, 0.f, 0.f, 0.f, 0.f, 0.f};
    const ushort8* hr8 = (const ushort8*)hr;
    for (int k = 0; k < nr; ++k) {
        int s = ell[base + k];
        ushort8 v = hr8[((size_t)s << lgc) + c];
#pragma unroll
        for (int j = 0; j < 8; ++j) acc[j] += b2f(v[j]);
    }
    float dnd = dn[d];
#pragma unroll
    for (int j = 0; j < 8; ++j) acc[j] *= dnd;
    if (mode >= 2) {
        int f = c << 3;
#pragma unroll
        for (int j = 0; j < 8; ++j)
            acc[j] += bias[f + j] + bias[dout + f + j] + bias[2 * dout + f + j];
    }
    if (mode >= 1) {
        ushort8 p = ((const ushort8*)outh)[i];
#pragma unroll
        for (int j = 0; j < 8; ++j) acc[j] += b2f(p[j]);
    }
    if (mode == 2) {
#pragma unroll
        for (int j = 0; j < 8; ++j) acc[j] = fmaxf(acc[j], 0.f);
    }
    ushort8 o;
#pragma unroll
    for (int j = 0; j < 8; ++j) o[j] = f2b(acc[j]);
    ((ushort8*)outh)[i] = o;
}

// ---------------- edge predictor: one wave per edge, bf16 h ----------------
__global__ __launch_bounds__(256) void predict_kernel(
        const unsigned short* __restrict__ h, const int* __restrict__ src,
        const int* __restrict__ dst,
        const float* __restrict__ Wp1, const float* __restrict__ bp1,
        const float* __restrict__ Wp2, const float* __restrict__ bp2,
        float* __restrict__ outp, int n_edges) {
    int gw   = (blockIdx.x * blockDim.x + threadIdx.x) >> 6;
    int lane = threadIdx.x & 63;
    if (gw >= n_edges) return;
    int s = src[gw], d = dst[gw];
    float zs = b2f(h[(size_t)s * 64 + lane]);
    float zd = b2f(h[(size_t)d * 64 + lane]);
    float acc = bp1[lane];
#pragma unroll 8
    for (int k = 0; k < 64; ++k)
        acc = fmaf(__shfl(zs, k), Wp1[k * 64 + lane], acc);
#pragma unroll 8
    for (int k = 0; k < 64; ++k)
        acc = fmaf(__shfl(zd, k), Wp1[(64 + k) * 64 + lane], acc);
    float t = fmaxf(acc, 0.f) * Wp2[lane];
#pragma unroll
    for (int off = 32; off; off >>= 1) t += __shfl_down(t, off);
    if (lane == 0) outp[gw] = t + bp2[0];
}

extern "C" void kernel_launch(void* const* d_in, const int* in_sizes, int n_in,
                              void* d_out, int out_size, void* d_ws, size_t ws_size,
                              hipStream_t stream) {
    const float* x       = (const float*)d_in[0];
    const int*   rel_src = (const int*)d_in[1];
    const int*   rel_dst = (const int*)d_in[2];
    const int*   pos_src = (const int*)d_in[3];
    const int*   pos_dst = (const int*)d_in[4];
    const int*   neg_src = (const int*)d_in[5];
    const int*   neg_dst = (const int*)d_in[6];
    const float* W[4]    = {(const float*)d_in[7],  (const float*)d_in[9],
                            (const float*)d_in[11], (const float*)d_in[13]};
    const float* bias[4] = {(const float*)d_in[8],  (const float*)d_in[10],
                            (const float*)d_in[12], (const float*)d_in[14]};
    const float* Wp1 = (const float*)d_in[15];
    const float* bp1 = (const float*)d_in[16];
    const float* Wp2 = (const float*)d_in[17];
    const float* bp2 = (const float*)d_in[18];
    float* out = (float*)d_out;

    // workspace layout (bf16 buffers padded +128 rows for OOB tile reads)
    size_t NP = (size_t)(N_NODES + 128);
    unsigned short* xb = (unsigned short*)d_ws;          // NP x 512
    unsigned short* h0 = xb + NP * 512;                  // NP x 512
    unsigned short* h1 = h0 + NP * 512;                  // NP x 256
    unsigned short* hr = h1 + NP * 256;                  // N x 512
    unsigned short* Wt = hr + (size_t)N_NODES * 512;     // 3*512*512 max
    float* sn   = (float*)(Wt + (size_t)R_REL * 512 * 512);
    float* dn   = sn + (size_t)R_REL * N_NODES;
    int* outcnt = (int*)(dn + (size_t)R_REL * N_NODES);
    int* incnt  = outcnt + (size_t)R_REL * N_NODES;
    int* ell    = incnt + (size_t)R_REL * N_NODES;

    hipMemsetAsync(outcnt, 0, sizeof(int) * 2 * R_REL * N_NODES, stream);
    count_fill_kernel<<<cdiv_h(R_REL * E_EDGES, 256), 256, 0, stream>>>(
        rel_src, rel_dst, outcnt, incnt, ell);
    norm_kernel<<<cdiv_h(R_REL * N_NODES, 256), 256, 0, stream>>>(outcnt, sn, R_REL * N_NODES);
    norm_kernel<<<cdiv_h(R_REL * N_NODES, 256), 256, 0, stream>>>(incnt, dn, R_REL * N_NODES);

    f2b8_kernel<<<cdiv_h(N_NODES * 512 / 8, 256), 256, 0, stream>>>(x, xb, N_NODES * 512 / 8);

    const int dims[5] = {512, 512, 256, 128, 64};
    unsigned short* hbufs[4] = {h0, h1, h0, h1};
    const unsigned short* hcur = xb;
    for (int l = 0; l < 4; ++l) {
        int din = dims[l], dout = dims[l + 1];
        unsigned short* hnext = hbufs[l];
        int wtot = R_REL * din * dout;
        wcvt_kernel<<<cdiv_h(wtot, 256), 256, 0, stream>>>(W[l], Wt, din, dout, wtot);
        int lgc = (dout == 512) ? 6 : (dout == 256) ? 5 : (dout == 128) ? 4 : 3; // log2(dout/8)
        int total = N_NODES << lgc;
        for (int r = 0; r < R_REL; ++r) {
            dim3 grid(dout / 64, cdiv_h(N_NODES, 128));
            gemm_bf16_kernel<<<grid, 256, 0, stream>>>(
                hcur, Wt + (size_t)r * din * dout, hr, sn + (size_t)r * N_NODES,
                N_NODES, din, dout);
            int mode = (r == 0) ? 0 : (r == 2 ? ((l < 3) ? 2 : 3) : 1);
            gather_kernel<<<cdiv_h(total, 256), 256, 0, stream>>>(
                hr, ell + ((size_t)r * N_NODES << 5), incnt + (size_t)r * N_NODES,
                dn + (size_t)r * N_NODES, bias[l], hnext, lgc, total, mode, dout);
        }
        hcur = hnext;
    }

    // edge predictor: one wave per edge
    int blocks = cdiv_h(EP_EDGES * 64, 256);
    predict_kernel<<<blocks, 256, 0, stream>>>(hcur, pos_src, pos_dst, Wp1, bp1, Wp2, bp2,
                                               out, EP_EDGES);
    predict_kernel<<<blocks, 256, 0, stream>>>(hcur, neg_src, neg_dst, Wp1, bp1, Wp2, bp2,
                                               out + EP_EDGES, EP_EDGES);
}

// Round 4
// 758.091 us; speedup vs baseline: 5.5249x; 1.4512x over previous
//
#include <hip/hip_runtime.h>

#define N_NODES  50000
#define R_REL    3
#define E_EDGES  50000
#define EP_EDGES 100000
#define ELL_CAP  32

typedef __attribute__((ext_vector_type(8))) short  short8;
typedef __attribute__((ext_vector_type(8))) unsigned short ushort8;
typedef __attribute__((ext_vector_type(4))) float  floatx4;

static inline int cdiv_h(int a, int b) { return (a + b - 1) / b; }

__device__ inline unsigned short f2b(float f) {
    union { float f; unsigned u; } v; v.f = f;
    return (unsigned short)((v.u + 0x7FFF + ((v.u >> 16) & 1)) >> 16);
}
__device__ inline float b2f(unsigned short h) {
    union { unsigned u; float f; } v; v.u = ((unsigned)h) << 16;
    return v.f;
}

#define GLDS16(gp, lp) __builtin_amdgcn_global_load_lds( \
    (const __attribute__((address_space(1))) void*)(gp), \
    (__attribute__((address_space(3))) void*)(lp), 16, 0, 0)

// ---------------- degree count + ELL fill ----------------
__global__ void count_fill_kernel(const int* __restrict__ src, const int* __restrict__ dst,
                                  int* __restrict__ outcnt, int* __restrict__ incnt,
                                  int* __restrict__ ell) {
    int i = blockIdx.x * blockDim.x + threadIdx.x;
    if (i >= R_REL * E_EDGES) return;
    int r = i / E_EDGES;
    int s = src[i], d = dst[i];
    atomicAdd(&outcnt[r * N_NODES + s], 1);
    int k = atomicAdd(&incnt[r * N_NODES + d], 1);
    if (k < ELL_CAP)
        ell[((size_t)(r * N_NODES + d) << 5) + k] = s;
}

__global__ void norm_kernel(const int* __restrict__ cnt, float* __restrict__ nrm, int n) {
    int i = blockIdx.x * blockDim.x + threadIdx.x;
    if (i < n) nrm[i] = rsqrtf(fmaxf((float)cnt[i], 1.0f));
}

// ---------------- fp32 -> bf16 (8 elems/thread) ----------------
__global__ void f2b8_kernel(const float* __restrict__ in, unsigned short* __restrict__ out,
                            int total8) {
    int i = blockIdx.x * blockDim.x + threadIdx.x;
    if (i >= total8) return;
    float4 a = ((const float4*)in)[2 * i];
    float4 b = ((const float4*)in)[2 * i + 1];
    ushort8 o;
    o[0] = f2b(a.x); o[1] = f2b(a.y); o[2] = f2b(a.z); o[3] = f2b(a.w);
    o[4] = f2b(b.x); o[5] = f2b(b.y); o[6] = f2b(b.z); o[7] = f2b(b.w);
    ((ushort8*)out)[i] = o;
}

// ---------------- W[r][k][n] fp32 -> Wt[r][n][k] bf16 ----------------
__global__ void wcvt_kernel(const float* __restrict__ W, unsigned short* __restrict__ Wt,
                            int K, int Nd, int total) {
    int i = blockIdx.x * blockDim.x + threadIdx.x;
    if (i >= total) return;
    int k = i % K;
    int rest = i / K;
    int n = rest % Nd;
    int r = rest / Nd;
    Wt[i] = f2b(W[((size_t)r * K + k) * Nd + n]);
}

// ---------------- Wp1[128][64] fp32 -> But[128][64] bf16, But[jo][k]: ----------------
// jo<64: Wp1[k][jo] (U half);  jo>=64: Wp1[64+k][jo-64] (V half)
__global__ void wp1cvt_kernel(const float* __restrict__ Wp1, unsigned short* __restrict__ But) {
    int i = blockIdx.x * blockDim.x + threadIdx.x;
    if (i >= 128 * 64) return;
    int k = i & 63;
    int jo = i >> 6;
    int j = jo & 63;
    int half = jo >> 6;
    But[i] = f2b(Wp1[(size_t)(half * 64 + k) * 64 + j]);
}

// ---------------- MFMA GEMM: C[m][n] = (A[m][:] . Bt[n][:]) * rowscale[m], bf16 in/out ----
// BM=128 BN=64 BK=32, 256 thr (4 waves). K%32==0, Nd%64==0. rowscale==nullptr -> 1.0
__global__ __launch_bounds__(256) void gemm_bf16_kernel(
        const unsigned short* __restrict__ A, const unsigned short* __restrict__ Bt,
        unsigned short* __restrict__ C, const float* __restrict__ rowscale,
        int M, int K, int Nd) {
    __shared__ unsigned short sm[4096 + 2048];   // As[128][32], Bs[64][32]
    unsigned short* As = sm;
    unsigned short* Bs = sm + 4096;

    const int tid  = threadIdx.x;
    const int w    = tid >> 6;
    const int lane = tid & 63;
    const int m0   = blockIdx.y * 128;
    const int n0   = blockIdx.x * 64;

    const int lr = lane >> 2;          // 0..15
    const int lc = (lane & 3) * 8;     // 16B chunks

    floatx4 acc[2][4];
#pragma unroll
    for (int i = 0; i < 2; ++i)
#pragma unroll
        for (int j = 0; j < 4; ++j) acc[i][j] = (floatx4){0.f, 0.f, 0.f, 0.f};

    const int ko   = (lane >> 4) * 8;
    const int mrow = lane & 15;

    for (int k0 = 0; k0 < K; k0 += 32) {
#pragma unroll
        for (int s = 0; s < 2; ++s) {
            int q = w + s * 4;
            GLDS16(A + (size_t)(m0 + q * 16 + lr) * K + k0 + lc, As + q * 512);
        }
        GLDS16(Bt + (size_t)(n0 + w * 16 + lr) * K + k0 + lc, Bs + w * 512);
        __syncthreads();

        short8 a0 = *(const short8*)&As[(w * 32 + mrow) * 32 + ko];
        short8 a1 = *(const short8*)&As[(w * 32 + 16 + mrow) * 32 + ko];
        short8 b0 = *(const short8*)&Bs[(mrow) * 32 + ko];
        short8 b1 = *(const short8*)&Bs[(16 + mrow) * 32 + ko];
        short8 b2 = *(const short8*)&Bs[(32 + mrow) * 32 + ko];
        short8 b3 = *(const short8*)&Bs[(48 + mrow) * 32 + ko];

        acc[0][0] = __builtin_amdgcn_mfma_f32_16x16x32_bf16(a0, b0, acc[0][0], 0, 0, 0);
        acc[0][1] = __builtin_amdgcn_mfma_f32_16x16x32_bf16(a0, b1, acc[0][1], 0, 0, 0);
        acc[0][2] = __builtin_amdgcn_mfma_f32_16x16x32_bf16(a0, b2, acc[0][2], 0, 0, 0);
        acc[0][3] = __builtin_amdgcn_mfma_f32_16x16x32_bf16(a0, b3, acc[0][3], 0, 0, 0);
        acc[1][0] = __builtin_amdgcn_mfma_f32_16x16x32_bf16(a1, b0, acc[1][0], 0, 0, 0);
        acc[1][1] = __builtin_amdgcn_mfma_f32_16x16x32_bf16(a1, b1, acc[1][1], 0, 0, 0);
        acc[1][2] = __builtin_amdgcn_mfma_f32_16x16x32_bf16(a1, b2, acc[1][2], 0, 0, 0);
        acc[1][3] = __builtin_amdgcn_mfma_f32_16x16x32_bf16(a1, b3, acc[1][3], 0, 0, 0);
        __syncthreads();
    }

    const int col   = n0 + (lane & 15);
    const int rbase = m0 + w * 32 + (lane >> 4) * 4;
#pragma unroll
    for (int mi = 0; mi < 2; ++mi) {
#pragma unroll
        for (int reg = 0; reg < 4; ++reg) {
            int row = rbase + mi * 16 + reg;
            if (row < M) {
                float rs = rowscale ? rowscale[row] : 1.0f;
#pragma unroll
                for (int nj = 0; nj < 4; ++nj)
                    C[(size_t)row * Nd + col + nj * 16] = f2b(acc[mi][nj][reg] * rs);
            }
        }
    }
}

// ---------------- fused 3-relation ELL gather + bias-sum + optional ReLU ----------------
__global__ void gather3_kernel(const unsigned short* __restrict__ hr, size_t hrStride,
                               const int* __restrict__ ell, const int* __restrict__ incnt,
                               const float* __restrict__ dn, const float* __restrict__ bias,
                               unsigned short* __restrict__ outh,
                               int lgc, int total, int do_relu, int dout) {
    int i = blockIdx.x * blockDim.x + threadIdx.x;
    if (i >= total) return;
    int d = i >> lgc;
    int c = i & ((1 << lgc) - 1);
    float acc[8] = {0.f, 0.f, 0.f, 0.f, 0.f, 0.f, 0.f, 0.f};
#pragma unroll
    for (int r = 0; r < R_REL; ++r) {
        int nr = incnt[r * N_NODES + d];
        nr = nr < ELL_CAP ? nr : ELL_CAP;
        size_t base = (size_t)(r * N_NODES + d) << 5;
        const ushort8* hr8 = (const ushort8*)(hr + r * hrStride);
        float a[8] = {0.f, 0.f, 0.f, 0.f, 0.f, 0.f, 0.f, 0.f};
        for (int k = 0; k < nr; ++k) {
            int s = ell[base + k];
            ushort8 v = hr8[((size_t)s << lgc) + c];
#pragma unroll
            for (int j = 0; j < 8; ++j) a[j] += b2f(v[j]);
        }
        float dnd = dn[r * N_NODES + d];
#pragma unroll
        for (int j = 0; j < 8; ++j) acc[j] += dnd * a[j];
    }
    int f = c << 3;
#pragma unroll
    for (int j = 0; j < 8; ++j)
        acc[j] += bias[f + j] + bias[dout + f + j] + bias[2 * dout + f + j];
    if (do_relu) {
#pragma unroll
        for (int j = 0; j < 8; ++j) acc[j] = fmaxf(acc[j], 0.f);
    }
    ushort8 o;
#pragma unroll
    for (int j = 0; j < 8; ++j) o[j] = f2b(acc[j]);
    ((ushort8*)outh)[i] = o;
}

// ---------------- edge scores from UV: score = Wp2 . relu(U[s]+V[d]+bp1) + bp2 ----------
// one thread per edge; pos edges i<EP, neg edges i>=EP
__global__ __launch_bounds__(256) void edge_score_kernel(
        const unsigned short* __restrict__ UV,
        const int* __restrict__ pos_src, const int* __restrict__ pos_dst,
        const int* __restrict__ neg_src, const int* __restrict__ neg_dst,
        const float* __restrict__ bp1, const float* __restrict__ Wp2,
        const float* __restrict__ bp2, float* __restrict__ outp) {
    __shared__ float sb[64], sw[64];
    int t = threadIdx.x;
    if (t < 64) { sb[t] = bp1[t]; sw[t] = Wp2[t]; }
    __syncthreads();
    int i = blockIdx.x * blockDim.x + t;
    if (i >= 2 * EP_EDGES) return;
    int s, d;
    if (i < EP_EDGES) { s = pos_src[i]; d = pos_dst[i]; }
    else              { s = neg_src[i - EP_EDGES]; d = neg_dst[i - EP_EDGES]; }
    const ushort8* UV8 = (const ushort8*)UV;
    float acc = bp2[0];
#pragma unroll
    for (int jv = 0; jv < 8; ++jv) {
        ushort8 u = UV8[(size_t)s * 16 + jv];
        ushort8 v = UV8[(size_t)d * 16 + 8 + jv];
#pragma unroll
        for (int j = 0; j < 8; ++j) {
            float z = b2f(u[j]) + b2f(v[j]) + sb[jv * 8 + j];
            acc = fmaf(fmaxf(z, 0.f), sw[jv * 8 + j], acc);
        }
    }
    outp[i] = acc;
}

extern "C" void kernel_launch(void* const* d_in, const int* in_sizes, int n_in,
                              void* d_out, int out_size, void* d_ws, size_t ws_size,
                              hipStream_t stream) {
    const float* x       = (const float*)d_in[0];
    const int*   rel_src = (const int*)d_in[1];
    const int*   rel_dst = (const int*)d_in[2];
    const int*   pos_src = (const int*)d_in[3];
    const int*   pos_dst = (const int*)d_in[4];
    const int*   neg_src = (const int*)d_in[5];
    const int*   neg_dst = (const int*)d_in[6];
    const float* W[4]    = {(const float*)d_in[7],  (const float*)d_in[9],
                            (const float*)d_in[11], (const float*)d_in[13]};
    const float* bias[4] = {(const float*)d_in[8],  (const float*)d_in[10],
                            (const float*)d_in[12], (const float*)d_in[14]};
    const float* Wp1 = (const float*)d_in[15];
    const float* bp1 = (const float*)d_in[16];
    const float* Wp2 = (const float*)d_in[17];
    const float* bp2 = (const float*)d_in[18];
    float* out = (float*)d_out;

    // workspace layout (bf16 buffers padded +128 rows for OOB tile reads)
    size_t NP = (size_t)(N_NODES + 128);
    unsigned short* xb  = (unsigned short*)d_ws;          // NP x 512 (reused for UV later)
    unsigned short* h0  = xb + NP * 512;                  // NP x 512
    unsigned short* h1  = h0 + NP * 512;                  // NP x 256
    unsigned short* hr  = h1 + NP * 256;                  // 3 x N x 512 (per-relation out)
    unsigned short* Wt  = hr + (size_t)R_REL * N_NODES * 512;   // 3*512*512
    unsigned short* But = Wt + (size_t)R_REL * 512 * 512;       // 128*64
    float* sn   = (float*)(But + 128 * 64);
    float* dn   = sn + (size_t)R_REL * N_NODES;
    int* outcnt = (int*)(dn + (size_t)R_REL * N_NODES);
    int* incnt  = outcnt + (size_t)R_REL * N_NODES;
    int* ell    = incnt + (size_t)R_REL * N_NODES;        // 3*N*32 ints
    unsigned short* UV = xb;                              // N x 128 (after layers done)

    hipMemsetAsync(outcnt, 0, sizeof(int) * 2 * R_REL * N_NODES, stream);
    count_fill_kernel<<<cdiv_h(R_REL * E_EDGES, 256), 256, 0, stream>>>(
        rel_src, rel_dst, outcnt, incnt, ell);
    norm_kernel<<<cdiv_h(R_REL * N_NODES, 256), 256, 0, stream>>>(outcnt, sn, R_REL * N_NODES);
    norm_kernel<<<cdiv_h(R_REL * N_NODES, 256), 256, 0, stream>>>(incnt, dn, R_REL * N_NODES);

    f2b8_kernel<<<cdiv_h(N_NODES * 512 / 8, 256), 256, 0, stream>>>(x, xb, N_NODES * 512 / 8);
    wp1cvt_kernel<<<cdiv_h(128 * 64, 256), 256, 0, stream>>>(Wp1, But);

    const int dims[5] = {512, 512, 256, 128, 64};
    unsigned short* hbufs[4] = {h0, h1, h0, h1};
    const unsigned short* hcur = xb;
    for (int l = 0; l < 4; ++l) {
        int din = dims[l], dout = dims[l + 1];
        unsigned short* hnext = hbufs[l];
        int wtot = R_REL * din * dout;
        wcvt_kernel<<<cdiv_h(wtot, 256), 256, 0, stream>>>(W[l], Wt, din, dout, wtot);
        size_t hrStride = (size_t)N_NODES * dout;
        dim3 grid(dout / 64, cdiv_h(N_NODES, 128));
        for (int r = 0; r < R_REL; ++r) {
            gemm_bf16_kernel<<<grid, 256, 0, stream>>>(
                hcur, Wt + (size_t)r * din * dout, hr + r * hrStride,
                sn + (size_t)r * N_NODES, N_NODES, din, dout);
        }
        int lgc = (dout == 512) ? 6 : (dout == 256) ? 5 : (dout == 128) ? 4 : 3; // log2(dout/8)
        int total = N_NODES << lgc;
        gather3_kernel<<<cdiv_h(total, 256), 256, 0, stream>>>(
            hr, hrStride, ell, incnt, dn, bias[l], hnext, lgc, total,
            (l < 3) ? 1 : 0, dout);
        hcur = hnext;
    }

    // UV = h_final @ [Wp1_top | Wp1_bot]  (M=N, K=64, Nd=128)
    dim3 uvgrid(2, cdiv_h(N_NODES, 128));
    gemm_bf16_kernel<<<uvgrid, 256, 0, stream>>>(hcur, But, UV, nullptr, N_NODES, 64, 128);

    edge_score_kernel<<<cdiv_h(2 * EP_EDGES, 256), 256, 0, stream>>>(
        UV, pos_src, pos_dst, neg_src, neg_dst, bp1, Wp2, bp2, out);
}

// Round 5
// 598.879 us; speedup vs baseline: 6.9938x; 1.2659x over previous
//
#include <hip/hip_runtime.h>

#define N_NODES  50000
#define R_REL    3
#define E_EDGES  50000
#define EP_EDGES 100000
#define ELL_CAP  32

typedef __attribute__((ext_vector_type(8))) short  short8;
typedef __attribute__((ext_vector_type(8))) unsigned short ushort8;
typedef __attribute__((ext_vector_type(4))) float  floatx4;

static inline int cdiv_h(int a, int b) { return (a + b - 1) / b; }

__device__ inline unsigned short f2b(float f) {
    union { float f; unsigned u; } v; v.f = f;
    return (unsigned short)((v.u + 0x7FFF + ((v.u >> 16) & 1)) >> 16);
}
__device__ inline float b2f(unsigned short h) {
    union { unsigned u; float f; } v; v.u = ((unsigned)h) << 16;
    return v.f;
}

#define GLDS16(gp, lp) __builtin_amdgcn_global_load_lds( \
    (const __attribute__((address_space(1))) void*)(gp), \
    (__attribute__((address_space(3))) void*)(lp), 16, 0, 0)

// ---------------- degree count + ELL fill ----------------
__global__ void count_fill_kernel(const int* __restrict__ src, const int* __restrict__ dst,
                                  int* __restrict__ outcnt, int* __restrict__ incnt,
                                  int* __restrict__ ell) {
    int i = blockIdx.x * blockDim.x + threadIdx.x;
    if (i >= R_REL * E_EDGES) return;
    int r = i / E_EDGES;
    int s = src[i], d = dst[i];
    atomicAdd(&outcnt[r * N_NODES + s], 1);
    int k = atomicAdd(&incnt[r * N_NODES + d], 1);
    if (k < ELL_CAP)
        ell[((size_t)(r * N_NODES + d) << 5) + k] = s;
}

__global__ void norm_kernel(const int* __restrict__ cnt, float* __restrict__ nrm, int n) {
    int i = blockIdx.x * blockDim.x + threadIdx.x;
    if (i < n) nrm[i] = rsqrtf(fmaxf((float)cnt[i], 1.0f));
}

// ---------------- fp32 -> bf16 (8 elems/thread) ----------------
__global__ void f2b8_kernel(const float* __restrict__ in, unsigned short* __restrict__ out,
                            int total8) {
    int i = blockIdx.x * blockDim.x + threadIdx.x;
    if (i >= total8) return;
    float4 a = ((const float4*)in)[2 * i];
    float4 b = ((const float4*)in)[2 * i + 1];
    ushort8 o;
    o[0] = f2b(a.x); o[1] = f2b(a.y); o[2] = f2b(a.z); o[3] = f2b(a.w);
    o[4] = f2b(b.x); o[5] = f2b(b.y); o[6] = f2b(b.z); o[7] = f2b(b.w);
    ((ushort8*)out)[i] = o;
}

// ---------------- W[r][k][n] fp32 -> Bt_all[r*dout+n][k] bf16, zero-pad rows >= 3*dout ----
__global__ void wcvt_kernel(const float* __restrict__ W, unsigned short* __restrict__ Wt,
                            int K, int dout, int total) {
    int i = blockIdx.x * blockDim.x + threadIdx.x;
    if (i >= total) return;
    int k = i % K;
    int nall = i / K;
    int r = nall / dout;
    int n = nall - r * dout;
    Wt[i] = (r < R_REL) ? f2b(W[((size_t)r * K + k) * dout + n]) : (unsigned short)0;
}

// ---------------- Wp1[128][64] fp32 -> But[128][64] bf16 ----------------
// row jo<64: Wp1[k][jo] (U half); jo>=64: Wp1[64+k][jo-64] (V half)
__global__ void wp1cvt_kernel(const float* __restrict__ Wp1, unsigned short* __restrict__ But) {
    int i = blockIdx.x * blockDim.x + threadIdx.x;
    if (i >= 128 * 64) return;
    int k = i & 63;
    int jo = i >> 6;
    int j = jo & 63;
    int half = jo >> 6;
    But[i] = f2b(Wp1[(size_t)(half * 64 + k) * 64 + j]);
}

// ---------------- fused MFMA GEMM: C[m][n] = (A[m][:].Bt[n][:]) * sn[n/dout][m] --------
// BM=128 BN=128 BK=32, 256 thr (4 waves, 2x2 quadrants, 4x4 16x16 tiles each).
// K%32==0, NdPad%128==0. sn==nullptr -> scale 1 (and no relation guard).
// XCD-locality swizzle: blocks p==j (mod 8) share one m-panel across all n-blocks.
__global__ __launch_bounds__(256) void gemm_bf16_fused(
        const unsigned short* __restrict__ A, const unsigned short* __restrict__ Bt,
        unsigned short* __restrict__ C, const float* __restrict__ sn,
        int M, int K, int NdPad, int dout) {
    __shared__ unsigned short As[4096];   // [128][32]
    __shared__ unsigned short Bs[4096];   // [128][32]

    const int nN = gridDim.x, nM = gridDim.y;
    int p = blockIdx.y * nN + blockIdx.x;
    const int nig = nN << 3;
    int group = p / nig;
    int rem = p - group * nig;
    int gs = nM - (group << 3); if (gs > 8) gs = 8;
    int mb = (group << 3) + rem % gs;
    int nb = rem / gs;
    const int m0 = mb * 128, n0 = nb * 128;

    const int tid  = threadIdx.x;
    const int w    = tid >> 6;
    const int lane = tid & 63;
    const int wm   = w & 1;          // quadrant row
    const int wn   = w >> 1;         // quadrant col
    const int lr   = lane >> 2;      // 0..15
    const int lc   = (lane & 3) * 8; // k-offset (ushorts) of 16B chunk

    floatx4 acc[4][4];
#pragma unroll
    for (int i = 0; i < 4; ++i)
#pragma unroll
        for (int j = 0; j < 4; ++j) acc[i][j] = (floatx4){0.f, 0.f, 0.f, 0.f};

    const int mrow = lane & 15;
    const int ko   = (lane >> 4) * 8;

    for (int k0 = 0; k0 < K; k0 += 32) {
        GLDS16(A  + (size_t)(m0 +      w * 16 + lr) * K + k0 + lc, As +        w * 512);
        GLDS16(A  + (size_t)(m0 + 64 + w * 16 + lr) * K + k0 + lc, As + 2048 + w * 512);
        GLDS16(Bt + (size_t)(n0 +      w * 16 + lr) * K + k0 + lc, Bs +        w * 512);
        GLDS16(Bt + (size_t)(n0 + 64 + w * 16 + lr) * K + k0 + lc, Bs + 2048 + w * 512);
        __syncthreads();

        short8 a[4], b[4];
#pragma unroll
        for (int mt = 0; mt < 4; ++mt)
            a[mt] = *(const short8*)&As[(wm * 64 + mt * 16 + mrow) * 32 + ko];
#pragma unroll
        for (int nt = 0; nt < 4; ++nt)
            b[nt] = *(const short8*)&Bs[(wn * 64 + nt * 16 + mrow) * 32 + ko];
#pragma unroll
        for (int mt = 0; mt < 4; ++mt)
#pragma unroll
            for (int nt = 0; nt < 4; ++nt)
                acc[mt][nt] = __builtin_amdgcn_mfma_f32_16x16x32_bf16(a[mt], b[nt],
                                                                      acc[mt][nt], 0, 0, 0);
        __syncthreads();
    }

    // epilogue: C/D layout col=lane&15, row=(lane>>4)*4+reg
    const int colb = n0 + wn * 64;
    const int r_quad = colb / dout;          // relation of this 64-col quadrant
    if (sn && r_quad >= R_REL) return;       // zero-pad columns: skip store
    const int col = colb + (lane & 15);
    const int rb0 = m0 + wm * 64 + (lane >> 4) * 4;
#pragma unroll
    for (int mt = 0; mt < 4; ++mt) {
#pragma unroll
        for (int reg = 0; reg < 4; ++reg) {
            int row = rb0 + mt * 16 + reg;
            if (row < M) {
                float rs = sn ? sn[(size_t)r_quad * N_NODES + row] : 1.0f;
#pragma unroll
                for (int nt = 0; nt < 4; ++nt)
                    C[(size_t)row * NdPad + col + nt * 16] = f2b(acc[mt][nt][reg] * rs);
            }
        }
    }
}

// ---------------- fused 3-relation ELL gather + bias-sum + optional ReLU ----------------
// hr rows are [rel0 | rel1 | rel2 | pad] with row stride S8 ushort8-chunks.
__global__ void gather3_kernel(const unsigned short* __restrict__ hr, int S8, int d8,
                               const int* __restrict__ ell, const int* __restrict__ incnt,
                               const float* __restrict__ dn, const float* __restrict__ bias,
                               unsigned short* __restrict__ outh,
                               int lgc, int total, int do_relu, int dout) {
    int i = blockIdx.x * blockDim.x + threadIdx.x;
    if (i >= total) return;
    int d = i >> lgc;
    int c = i & ((1 << lgc) - 1);
    float acc[8] = {0.f, 0.f, 0.f, 0.f, 0.f, 0.f, 0.f, 0.f};
    const ushort8* hr8 = (const ushort8*)hr;
#pragma unroll
    for (int r = 0; r < R_REL; ++r) {
        int nr = incnt[r * N_NODES + d];
        nr = nr < ELL_CAP ? nr : ELL_CAP;
        size_t base = (size_t)(r * N_NODES + d) << 5;
        float a[8] = {0.f, 0.f, 0.f, 0.f, 0.f, 0.f, 0.f, 0.f};
        for (int k = 0; k < nr; ++k) {
            int s = ell[base + k];
            ushort8 v = hr8[(size_t)s * S8 + r * d8 + c];
#pragma unroll
            for (int j = 0; j < 8; ++j) a[j] += b2f(v[j]);
        }
        float dnd = dn[r * N_NODES + d];
#pragma unroll
        for (int j = 0; j < 8; ++j) acc[j] += dnd * a[j];
    }
    int f = c << 3;
#pragma unroll
    for (int j = 0; j < 8; ++j)
        acc[j] += bias[f + j] + bias[dout + f + j] + bias[2 * dout + f + j];
    if (do_relu) {
#pragma unroll
        for (int j = 0; j < 8; ++j) acc[j] = fmaxf(acc[j], 0.f);
    }
    ushort8 o;
#pragma unroll
    for (int j = 0; j < 8; ++j) o[j] = f2b(acc[j]);
    ((ushort8*)outh)[i] = o;
}

// ---------------- edge scores from UV: score = Wp2 . relu(U[s]+V[d]+bp1) + bp2 ----------
__global__ __launch_bounds__(256) void edge_score_kernel(
        const unsigned short* __restrict__ UV,
        const int* __restrict__ pos_src, const int* __restrict__ pos_dst,
        const int* __restrict__ neg_src, const int* __restrict__ neg_dst,
        const float* __restrict__ bp1, const float* __restrict__ Wp2,
        const float* __restrict__ bp2, float* __restrict__ outp) {
    __shared__ float sb[64], sw[64];
    int t = threadIdx.x;
    if (t < 64) { sb[t] = bp1[t]; sw[t] = Wp2[t]; }
    __syncthreads();
    int i = blockIdx.x * blockDim.x + t;
    if (i >= 2 * EP_EDGES) return;
    int s, d;
    if (i < EP_EDGES) { s = pos_src[i]; d = pos_dst[i]; }
    else              { s = neg_src[i - EP_EDGES]; d = neg_dst[i - EP_EDGES]; }
    const ushort8* UV8 = (const ushort8*)UV;
    float acc = bp2[0];
#pragma unroll
    for (int jv = 0; jv < 8; ++jv) {
        ushort8 u = UV8[(size_t)s * 16 + jv];
        ushort8 v = UV8[(size_t)d * 16 + 8 + jv];
#pragma unroll
        for (int j = 0; j < 8; ++j) {
            float z = b2f(u[j]) + b2f(v[j]) + sb[jv * 8 + j];
            acc = fmaf(fmaxf(z, 0.f), sw[jv * 8 + j], acc);
        }
    }
    outp[i] = acc;
}

extern "C" void kernel_launch(void* const* d_in, const int* in_sizes, int n_in,
                              void* d_out, int out_size, void* d_ws, size_t ws_size,
                              hipStream_t stream) {
    const float* x       = (const float*)d_in[0];
    const int*   rel_src = (const int*)d_in[1];
    const int*   rel_dst = (const int*)d_in[2];
    const int*   pos_src = (const int*)d_in[3];
    const int*   pos_dst = (const int*)d_in[4];
    const int*   neg_src = (const int*)d_in[5];
    const int*   neg_dst = (const int*)d_in[6];
    const float* W[4]    = {(const float*)d_in[7],  (const float*)d_in[9],
                            (const float*)d_in[11], (const float*)d_in[13]};
    const float* bias[4] = {(const float*)d_in[8],  (const float*)d_in[10],
                            (const float*)d_in[12], (const float*)d_in[14]};
    const float* Wp1 = (const float*)d_in[15];
    const float* bp1 = (const float*)d_in[16];
    const float* Wp2 = (const float*)d_in[17];
    const float* bp2 = (const float*)d_in[18];
    float* out = (float*)d_out;

    // workspace layout (bf16 buffers padded +128 rows for OOB tile reads)
    size_t NP = (size_t)(N_NODES + 128);
    unsigned short* xb  = (unsigned short*)d_ws;          // NP x 512 (reused for UV later)
    unsigned short* h0  = xb + NP * 512;                  // NP x 512
    unsigned short* h1  = h0 + NP * 512;                  // NP x 256
    unsigned short* hr  = h1 + NP * 256;                  // N x 1536 max (fused C)
    unsigned short* Wt  = hr + (size_t)R_REL * N_NODES * 512;   // 1536*512 max
    unsigned short* But = Wt + (size_t)R_REL * 512 * 512;       // 128*64
    float* sn   = (float*)(But + 128 * 64);
    float* dn   = sn + (size_t)R_REL * N_NODES;
    int* outcnt = (int*)(dn + (size_t)R_REL * N_NODES);
    int* incnt  = outcnt + (size_t)R_REL * N_NODES;
    int* ell    = incnt + (size_t)R_REL * N_NODES;        // 3*N*32 ints
    unsigned short* UV = xb;                              // N x 128 (after layers done)

    hipMemsetAsync(outcnt, 0, sizeof(int) * 2 * R_REL * N_NODES, stream);
    count_fill_kernel<<<cdiv_h(R_REL * E_EDGES, 256), 256, 0, stream>>>(
        rel_src, rel_dst, outcnt, incnt, ell);
    norm_kernel<<<cdiv_h(R_REL * N_NODES, 256), 256, 0, stream>>>(outcnt, sn, R_REL * N_NODES);
    norm_kernel<<<cdiv_h(R_REL * N_NODES, 256), 256, 0, stream>>>(incnt, dn, R_REL * N_NODES);

    f2b8_kernel<<<cdiv_h(N_NODES * 512 / 8, 256), 256, 0, stream>>>(x, xb, N_NODES * 512 / 8);
    wp1cvt_kernel<<<cdiv_h(128 * 64, 256), 256, 0, stream>>>(Wp1, But);

    const int dims[5]  = {512, 512, 256, 128, 64};
    const int ndpad[4] = {1536, 768, 384, 256};   // 3*dout padded to x128
    unsigned short* hbufs[4] = {h0, h1, h0, h1};
    const unsigned short* hcur = xb;
    for (int l = 0; l < 4; ++l) {
        int din = dims[l], dout = dims[l + 1], NdPad = ndpad[l];
        unsigned short* hnext = hbufs[l];
        int wtot = NdPad * din;
        wcvt_kernel<<<cdiv_h(wtot, 256), 256, 0, stream>>>(W[l], Wt, din, dout, wtot);
        dim3 grid(NdPad / 128, cdiv_h(N_NODES, 128));
        gemm_bf16_fused<<<grid, 256, 0, stream>>>(hcur, Wt, hr, sn, N_NODES, din, NdPad, dout);
        int lgc = (dout == 512) ? 6 : (dout == 256) ? 5 : (dout == 128) ? 4 : 3; // log2(dout/8)
        int total = N_NODES << lgc;
        gather3_kernel<<<cdiv_h(total, 256), 256, 0, stream>>>(
            hr, NdPad / 8, dout / 8, ell, incnt, dn, bias[l], hnext, lgc, total,
            (l < 3) ? 1 : 0, dout);
        hcur = hnext;
    }

    // UV = h_final @ [Wp1_top | Wp1_bot]  (M=N, K=64, Nd=128)
    dim3 uvgrid(1, cdiv_h(N_NODES, 128));
    gemm_bf16_fused<<<uvgrid, 256, 0, stream>>>(hcur, But, UV, nullptr, N_NODES, 64, 128, 128);

    edge_score_kernel<<<cdiv_h(2 * EP_EDGES, 256), 256, 0, stream>>>(
        UV, pos_src, pos_dst, neg_src, neg_dst, bp1, Wp2, bp2, out);
}